// Round 1
// baseline (74.073 us; speedup 1.0000x reference)
//
#include <hip/hip_runtime.h>
#include <math.h>

#define NP 8192
#define SEQ 4
#define KNN 16
#define R2 1.0f
#define NBLK (NP / 4)                  // 2048 worker blocks, 1 wave per point
#define WIN 1024                       // candidates per staged window
#define SCALE (1.0f / (float)(SEQ * NP * KNN))
#define POISON 0xAAAAAAAAu             // harness re-poisons d_ws before EVERY launch

// Single dispatch, NBLK+1 blocks.
// Workers (b < NBLK): 4 waves, one query point each. The 1024-candidate
// window is staged into LDS ONCE per block (3 coalesced float4 loads per
// thread = 12 wave-instructions, vs 192 strided dword wave-loads in the
// previous version -> ~12x fewer L1 line requests), then all 4 waves scan
// from LDS. Stride-3-dword LDS reads are a 2-way bank alias (free on
// CDNA4). No fx/fy/fz[16] register arrays -> VGPRs fit in 64 ->
// __launch_bounds__(256,8) keeps 8 blocks/CU resident (grid drains in ~1
// generation instead of ~4). Window advance is a block-uniform decision
// via a shared flag so the staging barriers are always reached by all
// waves. Scan order (window-major, ballot-rank lane order) is identical
// to the reference scan order -> bit-exact.
// Finisher (b == NBLK): spins with relaxed agent-scope atomic loads until
// all partials differ from the poison bit-pattern, sums in fixed index
// order, writes out. NO fences — relaxed atomics only (fences emit L2
// writeback storms, +48 us in a previous session). Workers never wait on
// the finisher -> no deadlock regardless of scheduling.
__global__ __launch_bounds__(256, 8) void ballq_fused(
    const float* __restrict__ xyz,   // [NP,3]
    const float* __restrict__ pf,    // [SEQ,NP,3]
    float* __restrict__ partial,     // ws: NBLK floats, poison-initialized
    float* __restrict__ out)         // d_out[1]
{
    const int lane = threadIdx.x & 63;
    const int wv   = threadIdx.x >> 6;

    if (blockIdx.x == NBLK) {        // ---- finisher block ----
        float v[8];
        unsigned done = 0;
        const unsigned* up = (const unsigned*)partial;
        while (done != 0xFFu) {
#pragma unroll
            for (int r = 0; r < 8; ++r) {
                if (!(done & (1u << r))) {
                    const unsigned u = __hip_atomic_load(
                        &up[(r << 8) + threadIdx.x],
                        __ATOMIC_RELAXED, __HIP_MEMORY_SCOPE_AGENT);
                    if (u != POISON) { v[r] = __uint_as_float(u); done |= 1u << r; }
                }
            }
        }
        float s = 0.0f;
#pragma unroll
        for (int r = 0; r < 8; ++r) s += v[r];   // fixed order: deterministic
#pragma unroll
        for (int off = 32; off > 0; off >>= 1) s += __shfl_xor(s, off);
        __shared__ float w[4];
        if (lane == 0) w[wv] = s;
        __syncthreads();
        if (threadIdx.x == 0)
            out[0] = (w[0] + w[1] + w[2] + w[3]) * SCALE;
        return;
    }

    // ---- worker block: 4 waves, one query point each ----
    const int i = (blockIdx.x << 2) + wv;

    const float xi = xyz[3 * i + 0];
    const float yi = xyz[3 * i + 1];
    const float zi = xyz[3 * i + 2];

    // Hoist the scan-independent phase-2 loads: lane = k + 16*s reads its
    // own point's flow for seq s. Latency hides under the whole scan.
    const int s = lane >> 4;
    const size_t oi = ((size_t)s * NP + i) * 3;
    const float pix = pf[oi + 0];
    const float piy = pf[oi + 1];
    const float piz = pf[oi + 2];

    __shared__ float4 win4[(WIN * 3) / 4];   // 12 KiB staged window (AoS)
    __shared__ int slots[4][KNN];            // per-wave first-16 hit indices
    __shared__ int sdone;
    const float* win = (const float*)win4;

    int cnt = 0;                     // wave-uniform hits found so far

    for (int base = 0; base < NP; base += WIN) {
        // Cooperative stage: 256 threads x 3 float4 = 12 KiB, coalesced.
        const float4* src = (const float4*)(xyz + 3 * base);
#pragma unroll
        for (int t = 0; t < 3; ++t)
            win4[(t << 8) + threadIdx.x] = src[(t << 8) + threadIdx.x];
        if (threadIdx.x == 0) sdone = 1;
        __syncthreads();             // staging visible to all waves

        if (cnt < KNN) {             // wave-uniform: done waves idle here
#pragma unroll
            for (int u = 0; u < 16; ++u) {
                const int jl = (u << 6) + lane;      // index within window
                const float dx = win[3 * jl + 0] - xi;   // 2-way bank alias: free
                const float dy = win[3 * jl + 1] - yi;
                const float dz = win[3 * jl + 2] - zi;
                const bool hit = dx * dx + dy * dy + dz * dz < R2;
                const unsigned long long m = __ballot(hit);
                if (hit) {
                    const int rank = __builtin_amdgcn_mbcnt_hi(
                        (unsigned)(m >> 32),
                        __builtin_amdgcn_mbcnt_lo((unsigned)m, 0));
                    const int g = cnt + rank;
                    if (g < KNN) slots[wv][g] = base + jl;
                }
                cnt += __popcll(m);  // wave-uniform
            }
            if (cnt < KNN && lane == 0) sdone = 0;   // this wave needs more
        }
        __syncthreads();             // scans done before flag read / restage
        if (sdone) break;            // block-uniform exit
    }

    // Lane l takes slot (l & 15); pad with slot 0 (self-hit guarantees >=1).
    int si = lane & 15;
    if (si >= cnt) si = 0;
    const int j = slots[wv][si];

    // Phase 2: lane = k + 16*s -> one (seq s, neighbor k) distance term.
    const size_t oj = ((size_t)s * NP + j) * 3;
    const float dx = pix - pf[oj + 0];
    const float dy = piy - pf[oj + 1];
    const float dz = piz - pf[oj + 2];
    float d = sqrtf(fmaxf(dx * dx + dy * dy + dz * dz, 1e-24f));

#pragma unroll
    for (int off = 32; off > 0; off >>= 1) d += __shfl_xor(d, off);

    __shared__ float sacc[4];
    if (lane == 0) sacc[wv] = d;
    __syncthreads();
    if (threadIdx.x == 0) {
        const float p = sacc[0] + sacc[1] + sacc[2] + sacc[3];  // > 0 always
        __hip_atomic_store(&partial[blockIdx.x], p,
                           __ATOMIC_RELAXED, __HIP_MEMORY_SCOPE_AGENT);
    }
}

extern "C" void kernel_launch(void* const* d_in, const int* in_sizes, int n_in,
                              void* d_out, int out_size, void* d_ws, size_t ws_size,
                              hipStream_t stream) {
    const float* xyz = (const float*)d_in[0];  // pc_source [1,8192,3]
    const float* pf  = (const float*)d_in[1];  // pred_flow [4,8192,3]
    float* partial   = (float*)d_ws;           // NBLK floats (poison = signal)
    float* out       = (float*)d_out;

    ballq_fused<<<NBLK + 1, 256, 0, stream>>>(xyz, pf, partial, out);
}

// Round 2
// 69.654 us; speedup vs baseline: 1.0634x; 1.0634x over previous
//
#include <hip/hip_runtime.h>
#include <math.h>

#define NP 8192
#define SEQ 4
#define KNN 16
#define R2 1.0f
#define NBLK (NP / 4)                  // 2048 worker blocks, 1 wave per point
#define WIN 256                        // candidates per scan window (4 per lane)
#define SCALE (1.0f / (float)(SEQ * NP * KNN))
#define POISON 0xAAAAAAAAu             // harness re-poisons d_ws before EVERY launch

// Single dispatch, NBLK+1 blocks.
// Workers (b < NBLK): one wave per query point. Scan structure: 4
// candidates per lane via 3 float4 loads (lane l owns the 12 contiguous
// floats of candidates 4l..4l+3), so a window is 256 candidates with 3
// load instructions (vs 48 strided dwords per 1024 before). Wins:
//  - early-exit quantum 1024 -> 256: bulk waves (~100-300 candidates
//    needed) do ~4x less distance work;
//  - next window double-buffered in 12 VGPRs: stragglers that scan all
//    8192 candidates pay ONE latency exposure, not 8;
//  - per-wave window progression, NO barriers in the scan (the r1 LDS
//    version made stragglers restage cooperatively per window: regressed).
// Rank math for ascending-index order (candidate c = base + 4*lane + q):
//   rank(l,q) = sum_q' mbcnt(m_q') + sum_{q'<q} ownbit(m_q')  -- matches
// the reference scan order exactly, so selection stays bit-exact.
// Finisher (b == NBLK): spins with relaxed agent-scope atomic loads until
// all partials differ from the poison bit-pattern, sums in fixed index
// order, writes out. NO fences (agent-scope fences = L2 writeback storms,
// +48 us in an earlier session). Workers never wait on the finisher.
__device__ __forceinline__ int mbcnt64(unsigned long long m) {
    return __builtin_amdgcn_mbcnt_hi((unsigned)(m >> 32),
           __builtin_amdgcn_mbcnt_lo((unsigned)m, 0));
}

__global__ __launch_bounds__(256, 4) void ballq_fused(
    const float* __restrict__ xyz,   // [NP,3]
    const float* __restrict__ pf,    // [SEQ,NP,3]
    float* __restrict__ partial,     // ws: NBLK floats, poison-initialized
    float* __restrict__ out)         // d_out[1]
{
    const int lane = threadIdx.x & 63;
    const int wv   = threadIdx.x >> 6;

    if (blockIdx.x == NBLK) {        // ---- finisher block ----
        float v[8];
        unsigned done = 0;
        const unsigned* up = (const unsigned*)partial;
        while (done != 0xFFu) {
#pragma unroll
            for (int r = 0; r < 8; ++r) {
                if (!(done & (1u << r))) {
                    const unsigned u = __hip_atomic_load(
                        &up[(r << 8) + threadIdx.x],
                        __ATOMIC_RELAXED, __HIP_MEMORY_SCOPE_AGENT);
                    if (u != POISON) { v[r] = __uint_as_float(u); done |= 1u << r; }
                }
            }
        }
        float s = 0.0f;
#pragma unroll
        for (int r = 0; r < 8; ++r) s += v[r];   // fixed order: deterministic
#pragma unroll
        for (int off = 32; off > 0; off >>= 1) s += __shfl_xor(s, off);
        __shared__ float w[4];
        if (lane == 0) w[wv] = s;
        __syncthreads();
        if (threadIdx.x == 0)
            out[0] = (w[0] + w[1] + w[2] + w[3]) * SCALE;
        return;
    }

    // ---- worker block: 4 waves, one query point each ----
    const int i = (blockIdx.x << 2) + wv;

    const float xi = xyz[3 * i + 0];
    const float yi = xyz[3 * i + 1];
    const float zi = xyz[3 * i + 2];

    // Hoist the scan-independent phase-2 loads: lane = k + 16*s reads its
    // own point's flow for seq s. Latency hides under the whole scan.
    const int s = lane >> 4;
    const size_t oi = ((size_t)s * NP + i) * 3;
    const float pix = pf[oi + 0];
    const float piy = pf[oi + 1];
    const float piz = pf[oi + 2];

    __shared__ int slots[4][KNN];    // per-wave first-16 hit indices
    const float4* F = (const float4*)xyz;   // [NP*3/4], 16B-aligned input

    int cnt = 0;                     // wave-uniform hits found so far

    // Prologue: window 0. Lane l's float4s: 3*l, 3*l+1, 3*l+2.
    float4 A = F[3 * lane + 0];
    float4 B = F[3 * lane + 1];
    float4 C = F[3 * lane + 2];

    for (int base = 0; base < NP; base += WIN) {
        // Double-buffer: issue next window's 3 loads before processing.
        // Last iteration wraps to window 0 (valid memory, value unused).
        const int nf = ((3 * ((base + WIN) & (NP - 1))) >> 2) + 3 * lane;
        const float4 A2 = F[nf + 0];
        const float4 B2 = F[nf + 1];
        const float4 C2 = F[nf + 2];

        // Candidates c = base + 4*lane + q, q=0..3 (12 contiguous floats).
        const float dx0 = A.x - xi, dy0 = A.y - yi, dz0 = A.z - zi;
        const float dx1 = A.w - xi, dy1 = B.x - yi, dz1 = B.y - zi;
        const float dx2 = B.z - xi, dy2 = B.w - yi, dz2 = C.x - zi;
        const float dx3 = C.y - xi, dy3 = C.z - yi, dz3 = C.w - zi;
        const bool h0 = dx0 * dx0 + dy0 * dy0 + dz0 * dz0 < R2;
        const bool h1 = dx1 * dx1 + dy1 * dy1 + dz1 * dz1 < R2;
        const bool h2 = dx2 * dx2 + dy2 * dy2 + dz2 * dz2 < R2;
        const bool h3 = dx3 * dx3 + dy3 * dy3 + dz3 * dz3 < R2;
        const unsigned long long m0 = __ballot(h0);
        const unsigned long long m1 = __ballot(h1);
        const unsigned long long m2 = __ballot(h2);
        const unsigned long long m3 = __ballot(h3);

        // Ascending-index rank within the window: all q of lanes < l,
        // then earlier q of this lane.
        const int pre = mbcnt64(m0) + mbcnt64(m1) + mbcnt64(m2) + mbcnt64(m3);
        const int o0 = (int)((m0 >> lane) & 1ull);
        const int o1 = (int)((m1 >> lane) & 1ull);
        const int o2 = (int)((m2 >> lane) & 1ull);
        const int g0 = cnt + pre;
        const int g1 = g0 + o0;
        const int g2 = g1 + o1;
        const int g3 = g2 + o2;
        const int c0 = base + 4 * lane;
        if (h0 && g0 < KNN) slots[wv][g0] = c0 + 0;
        if (h1 && g1 < KNN) slots[wv][g1] = c0 + 1;
        if (h2 && g2 < KNN) slots[wv][g2] = c0 + 2;
        if (h3 && g3 < KNN) slots[wv][g3] = c0 + 3;

        cnt += __popcll(m0) + __popcll(m1) + __popcll(m2) + __popcll(m3);
        if (cnt >= KNN) break;       // wave-uniform early exit
        A = A2; B = B2; C = C2;
    }

    // Lane l takes slot (l & 15); pad with slot 0 (self-hit guarantees >=1).
    // Same-wave LDS write->read: compiler inserts lgkmcnt wait; no barrier.
    int si = lane & 15;
    if (si >= cnt) si = 0;
    const int j = slots[wv][si];

    // Phase 2: lane = k + 16*s -> one (seq s, neighbor k) distance term.
    const size_t oj = ((size_t)s * NP + j) * 3;
    const float dx = pix - pf[oj + 0];
    const float dy = piy - pf[oj + 1];
    const float dz = piz - pf[oj + 2];
    float d = sqrtf(fmaxf(dx * dx + dy * dy + dz * dz, 1e-24f));

#pragma unroll
    for (int off = 32; off > 0; off >>= 1) d += __shfl_xor(d, off);

    __shared__ float sacc[4];
    if (lane == 0) sacc[wv] = d;
    __syncthreads();
    if (threadIdx.x == 0) {
        const float p = sacc[0] + sacc[1] + sacc[2] + sacc[3];  // > 0 always
        __hip_atomic_store(&partial[blockIdx.x], p,
                           __ATOMIC_RELAXED, __HIP_MEMORY_SCOPE_AGENT);
    }
}

extern "C" void kernel_launch(void* const* d_in, const int* in_sizes, int n_in,
                              void* d_out, int out_size, void* d_ws, size_t ws_size,
                              hipStream_t stream) {
    const float* xyz = (const float*)d_in[0];  // pc_source [1,8192,3]
    const float* pf  = (const float*)d_in[1];  // pred_flow [4,8192,3]
    float* partial   = (float*)d_ws;           // NBLK floats (poison = signal)
    float* out       = (float*)d_out;

    ballq_fused<<<NBLK + 1, 256, 0, stream>>>(xyz, pf, partial, out);
}

// Round 3
// 69.265 us; speedup vs baseline: 1.0694x; 1.0056x over previous
//
#include <hip/hip_runtime.h>
#include <math.h>

#define NP 8192
#define SEQ 4
#define KNN 16
#define R2 1.0f
#define NBLK (NP / 4)                  // 2048 worker blocks, 1 wave per point
#define WIN 256                        // candidates per scan window (4 per lane)
#define SCALE (1.0f / (float)(SEQ * NP * KNN))
#define POISON 0xAAAAAAAAu             // harness re-poisons d_ws before EVERY launch

// Single dispatch, NBLK+1 blocks. 2048 worker blocks == exactly 8/CU x 256
// CUs at __launch_bounds__(256,8), so the WHOLE grid is resident in one
// generation (r2 ran 2 generations at 4/CU): stragglers all start at t=0.
// To fit VGPR<=64 the r2 full double-buffer (24 VGPRs of window state) is
// replaced by prefetch-after-consume: compute the 4 d^2 (consuming A..C),
// immediately overwrite A..C with next window's loads, then do
// ballot/rank/slots/cnt while the loads fly. Single 12-VGPR window buffer;
// stragglers expose ~150 L2-warm cycles/window (~2 us worst case over 32
// windows), repaid by single-generation drain.
// Scan order (window-major, 4-candidates-per-lane, ballot-rank ascending)
// is identical to the reference scan order -> selection is bit-exact.
// Finisher (b == NBLK): spins with relaxed agent-scope atomic loads until
// all partials differ from the poison bit-pattern (the value itself is
// the signal -> no fences; agent-scope fences emit L2 writeback storms,
// +48 us in an earlier session), s_sleep(2) backoff per round to keep the
// spin off the fabric, sums in fixed index order, writes out. Workers
// never wait on the finisher -> no deadlock regardless of scheduling.
__device__ __forceinline__ int mbcnt64(unsigned long long m) {
    return __builtin_amdgcn_mbcnt_hi((unsigned)(m >> 32),
           __builtin_amdgcn_mbcnt_lo((unsigned)m, 0));
}

__global__ __launch_bounds__(256, 8) void ballq_fused(
    const float* __restrict__ xyz,   // [NP,3]
    const float* __restrict__ pf,    // [SEQ,NP,3]
    float* __restrict__ partial,     // ws: NBLK floats, poison-initialized
    float* __restrict__ out)         // d_out[1]
{
    const int lane = threadIdx.x & 63;
    const int wv   = threadIdx.x >> 6;

    if (blockIdx.x == NBLK) {        // ---- finisher block ----
        float v[8];
        unsigned done = 0;
        const unsigned* up = (const unsigned*)partial;
        while (done != 0xFFu) {
#pragma unroll
            for (int r = 0; r < 8; ++r) {
                if (!(done & (1u << r))) {
                    const unsigned u = __hip_atomic_load(
                        &up[(r << 8) + threadIdx.x],
                        __ATOMIC_RELAXED, __HIP_MEMORY_SCOPE_AGENT);
                    if (u != POISON) { v[r] = __uint_as_float(u); done |= 1u << r; }
                }
            }
            if (done != 0xFFu) __builtin_amdgcn_s_sleep(2);  // poll backoff
        }
        float s = 0.0f;
#pragma unroll
        for (int r = 0; r < 8; ++r) s += v[r];   // fixed order: deterministic
#pragma unroll
        for (int off = 32; off > 0; off >>= 1) s += __shfl_xor(s, off);
        __shared__ float w[4];
        if (lane == 0) w[wv] = s;
        __syncthreads();
        if (threadIdx.x == 0)
            out[0] = (w[0] + w[1] + w[2] + w[3]) * SCALE;
        return;
    }

    // ---- worker block: 4 waves, one query point each ----
    const int i = (blockIdx.x << 2) + wv;

    const float xi = xyz[3 * i + 0];
    const float yi = xyz[3 * i + 1];
    const float zi = xyz[3 * i + 2];

    // Hoist the scan-independent phase-2 loads: lane = k + 16*s reads its
    // own point's flow for seq s. Latency hides under the whole scan.
    const int s = lane >> 4;
    const size_t oi = ((size_t)s * NP + i) * 3;
    const float pix = pf[oi + 0];
    const float piy = pf[oi + 1];
    const float piz = pf[oi + 2];

    __shared__ int slots[4][KNN];    // per-wave first-16 hit indices
    const float4* F = (const float4*)xyz;   // [NP*3/4], 16B-aligned input

    int cnt = 0;                     // wave-uniform hits found so far

    // Window 0: lane l owns candidates 4l..4l+3 = float4s 3l, 3l+1, 3l+2.
    float4 A = F[3 * lane + 0];
    float4 B = F[3 * lane + 1];
    float4 C = F[3 * lane + 2];

    for (int base = 0; base < NP; base += WIN) {
        // Consume A..C into the four squared distances FIRST...
        float dx, dy, dz;
        dx = A.x - xi; dy = A.y - yi; dz = A.z - zi;
        const float e0 = dx * dx + dy * dy + dz * dz;
        dx = A.w - xi; dy = B.x - yi; dz = B.y - zi;
        const float e1 = dx * dx + dy * dy + dz * dz;
        dx = B.z - xi; dy = B.w - yi; dz = C.x - zi;
        const float e2 = dx * dx + dy * dy + dz * dz;
        dx = C.y - xi; dy = C.z - yi; dz = C.w - zi;
        const float e3 = dx * dx + dy * dy + dz * dz;

        // ...then immediately refill A..C with the next window (wraps to
        // window 0 on the last iteration: valid memory, value unused).
        // The ballot/rank/slot bookkeeping below hides the load latency.
        const int nf = ((3 * ((base + WIN) & (NP - 1))) >> 2) + 3 * lane;
        A = F[nf + 0];
        B = F[nf + 1];
        C = F[nf + 2];

        const bool h0 = e0 < R2;
        const bool h1 = e1 < R2;
        const bool h2 = e2 < R2;
        const bool h3 = e3 < R2;
        const unsigned long long m0 = __ballot(h0);
        const unsigned long long m1 = __ballot(h1);
        const unsigned long long m2 = __ballot(h2);
        const unsigned long long m3 = __ballot(h3);

        // Ascending-index rank within the window: all q of lanes < l,
        // then earlier q of this lane.
        const int pre = mbcnt64(m0) + mbcnt64(m1) + mbcnt64(m2) + mbcnt64(m3);
        const int o0 = (int)((m0 >> lane) & 1ull);
        const int o1 = (int)((m1 >> lane) & 1ull);
        const int o2 = (int)((m2 >> lane) & 1ull);
        const int g0 = cnt + pre;
        const int g1 = g0 + o0;
        const int g2 = g1 + o1;
        const int g3 = g2 + o2;
        const int c0 = base + 4 * lane;
        if (h0 && g0 < KNN) slots[wv][g0] = c0 + 0;
        if (h1 && g1 < KNN) slots[wv][g1] = c0 + 1;
        if (h2 && g2 < KNN) slots[wv][g2] = c0 + 2;
        if (h3 && g3 < KNN) slots[wv][g3] = c0 + 3;

        cnt += __popcll(m0) + __popcll(m1) + __popcll(m2) + __popcll(m3);
        if (cnt >= KNN) break;       // wave-uniform early exit
    }

    // Lane l takes slot (l & 15); pad with slot 0 (self-hit guarantees >=1).
    // Same-wave LDS write->read: compiler inserts lgkmcnt wait; no barrier.
    int si = lane & 15;
    if (si >= cnt) si = 0;
    const int j = slots[wv][si];

    // Phase 2: lane = k + 16*s -> one (seq s, neighbor k) distance term.
    const size_t oj = ((size_t)s * NP + j) * 3;
    const float dx = pix - pf[oj + 0];
    const float dy = piy - pf[oj + 1];
    const float dz = piz - pf[oj + 2];
    float d = sqrtf(fmaxf(dx * dx + dy * dy + dz * dz, 1e-24f));

#pragma unroll
    for (int off = 32; off > 0; off >>= 1) d += __shfl_xor(d, off);

    __shared__ float sacc[4];
    if (lane == 0) sacc[wv] = d;
    __syncthreads();
    if (threadIdx.x == 0) {
        const float p = sacc[0] + sacc[1] + sacc[2] + sacc[3];  // > 0 always
        __hip_atomic_store(&partial[blockIdx.x], p,
                           __ATOMIC_RELAXED, __HIP_MEMORY_SCOPE_AGENT);
    }
}

extern "C" void kernel_launch(void* const* d_in, const int* in_sizes, int n_in,
                              void* d_out, int out_size, void* d_ws, size_t ws_size,
                              hipStream_t stream) {
    const float* xyz = (const float*)d_in[0];  // pc_source [1,8192,3]
    const float* pf  = (const float*)d_in[1];  // pred_flow [4,8192,3]
    float* partial   = (float*)d_ws;           // NBLK floats (poison = signal)
    float* out       = (float*)d_out;

    ballq_fused<<<NBLK + 1, 256, 0, stream>>>(xyz, pf, partial, out);
}